// Round 5
// baseline (287.328 us; speedup 1.0000x reference)
//
#include <hip/hip_runtime.h>

#define D_IN 384
#define HID 64
#define NLAYERS 3
#define KSTEPS_IN (D_IN / 32)   // 12
#define BKT_BITS 9
#define BKT_SIZE (1 << BKT_BITS)   // 512 nodes per bucket
#define BKT_CAP 12288              // fixed region capacity (mean 8192, +45 sigma)
#define CHUNK 4096                 // edges per phaseA block

typedef __attribute__((ext_vector_type(8))) short bf16x8;
typedef __attribute__((ext_vector_type(4))) float f32x4;
typedef __attribute__((ext_vector_type(4))) unsigned short us4;
typedef unsigned short u16;

__device__ __forceinline__ u16 f2bf(float f) {
    union { float f; unsigned u; } v; v.f = f;
    unsigned u = v.u;
    return (u16)((u + 0x7fffu + ((u >> 16) & 1u)) >> 16);  // RNE
}
__device__ __forceinline__ float bf2f(u16 b) {
    union { unsigned u; float f; } v; v.u = ((unsigned)b) << 16;
    return v.f;
}

// ---------------- input projection: h = relu(x @ W_in + b_in), bf16 out ----------------
__global__ __launch_bounds__(256) void proj_mfma(const float* __restrict__ x,
                                                 const float* __restrict__ W,
                                                 const float* __restrict__ b,
                                                 u16* __restrict__ h, int N,
                                                 int* __restrict__ curA, int nbuk) {
    if (blockIdx.x == 0 && threadIdx.x < (unsigned)nbuk) curA[threadIdx.x] = 0;

    __shared__ u16 sB[KSTEPS_IN * 4 * 64 * 8];   // fragment-ordered W, 48 KB
    const int t = threadIdx.x;
    const int lane = t & 63;
    const int w = t >> 6;

    for (int fi = t; fi < KSTEPS_IN * 4 * 64; fi += 256) {
        int l  = fi & 63;
        int ct = (fi >> 6) & 3;
        int ks = fi >> 8;
        int kbase = ks * 32 + (l >> 4) * 8;
        int col   = ct * 16 + (l & 15);
        u16* d = &sB[(size_t)fi * 8];
        #pragma unroll
        for (int i = 0; i < 8; i++)
            d[i] = f2bf(W[(size_t)(kbase + i) * HID + col]);
    }
    __syncthreads();

    const int row0 = blockIdx.x * 256 + w * 64;
    f32x4 acc[4][4] = {};

    for (int ks = 0; ks < KSTEPS_IN; ks++) {
        bf16x8 a[4];
        #pragma unroll
        for (int rt = 0; rt < 4; rt++) {
            int row = row0 + rt * 16 + (lane & 15);
            if (row >= N) row = N - 1;
            const float* p = &x[(size_t)row * D_IN + ks * 32 + (lane >> 4) * 8];
            f32x4 x0 = *(const f32x4*)p;
            f32x4 x1 = *(const f32x4*)(p + 4);
            bf16x8 aa;
            aa[0] = (short)f2bf(x0[0]); aa[1] = (short)f2bf(x0[1]);
            aa[2] = (short)f2bf(x0[2]); aa[3] = (short)f2bf(x0[3]);
            aa[4] = (short)f2bf(x1[0]); aa[5] = (short)f2bf(x1[1]);
            aa[6] = (short)f2bf(x1[2]); aa[7] = (short)f2bf(x1[3]);
            a[rt] = aa;
        }
        #pragma unroll
        for (int ct = 0; ct < 4; ct++) {
            bf16x8 bb = *(const bf16x8*)&sB[(size_t)((ks * 4 + ct) * 64 + lane) * 8];
            #pragma unroll
            for (int rt = 0; rt < 4; rt++)
                acc[rt][ct] = __builtin_amdgcn_mfma_f32_16x16x32_bf16(a[rt], bb, acc[rt][ct], 0, 0, 0);
        }
    }

    float bias[4];
    #pragma unroll
    for (int ct = 0; ct < 4; ct++) bias[ct] = b[ct * 16 + (lane & 15)];

    #pragma unroll
    for (int rt = 0; rt < 4; rt++) {
        #pragma unroll
        for (int reg = 0; reg < 4; reg++) {
            int row = row0 + rt * 16 + (lane >> 4) * 4 + reg;
            if (row < N) {
                #pragma unroll
                for (int ct = 0; ct < 4; ct++) {
                    int col = ct * 16 + (lane & 15);
                    float v = acc[rt][ct][reg] + bias[ct];
                    h[(size_t)row * HID + col] = f2bf(fmaxf(v, 0.f));
                }
            }
        }
    }
}

// ---------------- CSR build: single-pass binning into fixed-capacity regions --------
__global__ __launch_bounds__(256) void phaseA(const int* __restrict__ src,
                                              const int* __restrict__ dst, int E,
                                              int* __restrict__ curA,
                                              unsigned* __restrict__ packed, int nbuk) {
    __shared__ int hist[256];
    __shared__ int sc[256];
    __shared__ int lbase[256];
    __shared__ int gbase[256];
    __shared__ int lcur[256];
    __shared__ unsigned buf[CHUNK];
    __shared__ unsigned char bid[CHUNK];
    const int t = threadIdx.x;
    const int e0 = blockIdx.x * CHUNK;
    const int cnt = min(CHUNK, E - e0);

    if (t < nbuk) hist[t] = 0;
    __syncthreads();

    unsigned pk[CHUNK / 256];
    int bk[CHUNK / 256];
    #pragma unroll
    for (int j = 0; j < CHUNK / 256; j++) {
        int idx = j * 256 + t;
        if (idx < cnt) {
            int e = e0 + idx;
            int d = dst[e];
            int s = src[e];
            bk[j] = d >> BKT_BITS;
            pk[j] = ((unsigned)s << BKT_BITS) | (unsigned)(d & (BKT_SIZE - 1));
            atomicAdd(&hist[bk[j]], 1);
        } else bk[j] = -1;
    }
    __syncthreads();
    sc[t] = (t < nbuk) ? hist[t] : 0;
    __syncthreads();
    for (int o = 1; o < 256; o <<= 1) {
        int v = (t >= o) ? sc[t - o] : 0;
        __syncthreads();
        sc[t] += v;
        __syncthreads();
    }
    if (t < nbuk) {
        lbase[t] = sc[t] - hist[t];
        lcur[t] = 0;
        gbase[t] = hist[t] ? (t * BKT_CAP + atomicAdd(&curA[t], hist[t])) : 0;
    }
    __syncthreads();
    #pragma unroll
    for (int j = 0; j < CHUNK / 256; j++) {
        if (bk[j] >= 0) {
            int r = atomicAdd(&lcur[bk[j]], 1);
            int slot = lbase[bk[j]] + r;
            buf[slot] = pk[j];
            bid[slot] = (unsigned char)bk[j];
        }
    }
    __syncthreads();
    for (int j = t; j < cnt; j += 256) {
        int b = bid[j];
        packed[gbase[b] + (j - lbase[b])] = buf[j];
    }
}

__global__ __launch_bounds__(256) void phaseB(const unsigned* __restrict__ packed,
                                              const int* __restrict__ curA,
                                              int N,
                                              int* __restrict__ ssorted,
                                              int* __restrict__ begs,
                                              int* __restrict__ ends,
                                              float* __restrict__ rdeg) {
    __shared__ int ldeg[BKT_SIZE];
    __shared__ int s[BKT_SIZE];
    __shared__ int lcur[BKT_SIZE];
    const int b = blockIdx.x;
    const int t = threadIdx.x;
    const int rb = b * BKT_CAP;
    const int cnt = curA[b];
    for (int i = t; i < BKT_SIZE; i += 256) ldeg[i] = 0;
    __syncthreads();
    for (int j = t; j < cnt; j += 256)
        atomicAdd(&ldeg[packed[rb + j] & (BKT_SIZE - 1)], 1);
    __syncthreads();
    for (int i = t; i < BKT_SIZE; i += 256) s[i] = ldeg[i];
    __syncthreads();
    for (int o = 1; o < BKT_SIZE; o <<= 1) {
        int v0 = (t >= o) ? s[t - o] : 0;
        int i1 = t + 256;
        int v1 = (i1 >= o) ? s[i1 - o] : 0;
        __syncthreads();
        s[t] += v0;
        s[i1] += v1;
        __syncthreads();
    }
    const int n0 = b << BKT_BITS;
    for (int i = t; i < BKT_SIZE; i += 256) {
        int excl = (i == 0) ? 0 : s[i - 1];
        lcur[i] = excl;
        int n = n0 + i;
        if (n < N) {
            begs[n] = rb + excl;
            ends[n] = rb + excl + ldeg[i];
            rdeg[n] = 1.0f / (float)max(ldeg[i], 1);
        }
    }
    __syncthreads();
    for (int j = t; j < cnt; j += 256) {
        unsigned p = packed[rb + j];
        int l = p & (BKT_SIZE - 1);
        int r = atomicAdd(&lcur[l], 1);
        ssorted[rb + r] = (int)(p >> BKT_BITS);
    }
}

// ---------------- mean aggregation: 8-way unrolled gathers (MLP=8) ----------------
__global__ __launch_bounds__(256) void agg_kernel(const u16* __restrict__ h,
                                                  const int* __restrict__ begs,
                                                  const int* __restrict__ ends,
                                                  const float* __restrict__ rdeg,
                                                  const int* __restrict__ ssorted,
                                                  u16* __restrict__ agg, int N) {
    const int lane = threadIdx.x & 63;
    const int wid  = (blockIdx.x * blockDim.x + threadIdx.x) >> 6;
    const int nw   = (gridDim.x * blockDim.x) >> 6;
    const int sub  = lane >> 4;
    const int cg   = lane & 15;
    for (int i = wid; i < N; i += nw) {
        const int beg = begs[i], end = ends[i];
        float a0 = 0.f, a1 = 0.f, a2 = 0.f, a3 = 0.f;
        for (int e0 = beg; e0 < end; e0 += 32) {
            const int eb = e0 + sub;
            float p[8];
            int idx[8];
            #pragma unroll
            for (int u = 0; u < 8; u++) {
                int j = eb + u * 4;
                p[u] = (j < end) ? 1.f : 0.f;
                idx[u] = min(j, end - 1);
            }
            int sn[8];
            #pragma unroll
            for (int u = 0; u < 8; u++) sn[u] = ssorted[idx[u]];
            us4 v[8];
            #pragma unroll
            for (int u = 0; u < 8; u++)
                v[u] = *(const us4*)&h[(size_t)sn[u] * HID + cg * 4];
            #pragma unroll
            for (int u = 0; u < 8; u++) {
                a0 += p[u] * bf2f(v[u][0]);
                a1 += p[u] * bf2f(v[u][1]);
                a2 += p[u] * bf2f(v[u][2]);
                a3 += p[u] * bf2f(v[u][3]);
            }
        }
        #pragma unroll
        for (int m = 16; m < 64; m <<= 1) {
            a0 += __shfl_xor(a0, m);
            a1 += __shfl_xor(a1, m);
            a2 += __shfl_xor(a2, m);
            a3 += __shfl_xor(a3, m);
        }
        if (lane < 16) {
            float r = rdeg[i];
            us4 o;
            o[0] = f2bf(a0 * r); o[1] = f2bf(a1 * r);
            o[2] = f2bf(a2 * r); o[3] = f2bf(a3 * r);
            *(us4*)&agg[(size_t)i * HID + cg * 4] = o;
        }
    }
}

// ---------------- fused SAGE layer via MFMA (LAST also applies output LN -> f32) ----
template<bool LAST>
__global__ __launch_bounds__(256) void layer_mfma(const u16* __restrict__ hin,
                                                  const u16* __restrict__ agg,
                                                  const float* __restrict__ Wl,
                                                  const float* __restrict__ Wr,
                                                  const float* __restrict__ bl,
                                                  const float* __restrict__ lng,
                                                  const float* __restrict__ lnb,
                                                  const float* __restrict__ og,
                                                  const float* __restrict__ ob,
                                                  u16* __restrict__ hout,
                                                  float* __restrict__ fout, int N) {
    __shared__ u16 sB[4 * 4 * 64 * 8];
    const int t = threadIdx.x;
    const int lane = t & 63;
    const int w = t >> 6;

    for (int fi = t; fi < 4 * 4 * 64; fi += 256) {
        int l  = fi & 63;
        int ct = (fi >> 6) & 3;
        int ks = fi >> 8;
        int kbase = ks * 32 + (l >> 4) * 8;
        int col   = ct * 16 + (l & 15);
        u16* d = &sB[(size_t)fi * 8];
        #pragma unroll
        for (int i = 0; i < 8; i++) {
            int kk = kbase + i;
            float wv = (kk < 64) ? Wl[(size_t)kk * HID + col]
                                 : Wr[(size_t)(kk - 64) * HID + col];
            d[i] = f2bf(wv);
        }
    }
    __syncthreads();

    const int row0 = blockIdx.x * 256 + w * 64;
    f32x4 acc[4][4] = {};

    #pragma unroll
    for (int ks = 0; ks < 4; ks++) {
        const u16* srcp = (ks < 2) ? agg : hin;
        const int ch0 = (ks & 1) * 32 + (lane >> 4) * 8;
        bf16x8 a[4];
        #pragma unroll
        for (int rt = 0; rt < 4; rt++) {
            int row = row0 + rt * 16 + (lane & 15);
            if (row >= N) row = N - 1;
            a[rt] = *(const bf16x8*)&srcp[(size_t)row * HID + ch0];
        }
        #pragma unroll
        for (int ct = 0; ct < 4; ct++) {
            bf16x8 bb = *(const bf16x8*)&sB[(size_t)((ks * 4 + ct) * 64 + lane) * 8];
            #pragma unroll
            for (int rt = 0; rt < 4; rt++)
                acc[rt][ct] = __builtin_amdgcn_mfma_f32_16x16x32_bf16(a[rt], bb, acc[rt][ct], 0, 0, 0);
        }
    }

    float bias[4], g4[4], be4[4], og4[4], ob4[4];
    #pragma unroll
    for (int ct = 0; ct < 4; ct++) {
        int c = ct * 16 + (lane & 15);
        bias[ct] = bl[c]; g4[ct] = lng[c]; be4[ct] = lnb[c];
        if (LAST) { og4[ct] = og[c]; ob4[ct] = ob[c]; }
    }

    #pragma unroll
    for (int rt = 0; rt < 4; rt++) {
        #pragma unroll
        for (int reg = 0; reg < 4; reg++) {
            int row = row0 + rt * 16 + (lane >> 4) * 4 + reg;
            if (row < N) {
                float v[4];
                float ss = 0.f;
                #pragma unroll
                for (int ct = 0; ct < 4; ct++) {
                    v[ct] = acc[rt][ct][reg] + bias[ct];
                    ss += v[ct] * v[ct];
                }
                #pragma unroll
                for (int m = 1; m < 16; m <<= 1) ss += __shfl_xor(ss, m);
                float rn = rsqrtf(fmaxf(ss, 1e-24f));
                float t4[4];
                float mean = 0.f;
                #pragma unroll
                for (int ct = 0; ct < 4; ct++) {
                    float o = fmaxf(v[ct] * rn, 0.f);
                    float hres = bf2f(hin[(size_t)row * HID + ct * 16 + (lane & 15)]);
                    t4[ct] = o + hres;
                    mean += t4[ct];
                }
                #pragma unroll
                for (int m = 1; m < 16; m <<= 1) mean += __shfl_xor(mean, m);
                mean *= (1.f / 64.f);
                float var = 0.f;
                #pragma unroll
                for (int ct = 0; ct < 4; ct++) {
                    float d = t4[ct] - mean;
                    var += d * d;
                }
                #pragma unroll
                for (int m = 1; m < 16; m <<= 1) var += __shfl_xor(var, m);
                var *= (1.f / 64.f);
                float rv = rsqrtf(var + 1e-5f);
                if (!LAST) {
                    #pragma unroll
                    for (int ct = 0; ct < 4; ct++)
                        hout[(size_t)row * HID + ct * 16 + (lane & 15)] =
                            f2bf((t4[ct] - mean) * rv * g4[ct] + be4[ct]);
                } else {
                    float y[4];
                    float m2 = 0.f;
                    #pragma unroll
                    for (int ct = 0; ct < 4; ct++) {
                        y[ct] = (t4[ct] - mean) * rv * g4[ct] + be4[ct];
                        m2 += y[ct];
                    }
                    #pragma unroll
                    for (int m = 1; m < 16; m <<= 1) m2 += __shfl_xor(m2, m);
                    m2 *= (1.f / 64.f);
                    float v2 = 0.f;
                    #pragma unroll
                    for (int ct = 0; ct < 4; ct++) {
                        float d = y[ct] - m2;
                        v2 += d * d;
                    }
                    #pragma unroll
                    for (int m = 1; m < 16; m <<= 1) v2 += __shfl_xor(v2, m);
                    v2 *= (1.f / 64.f);
                    float rv2 = rsqrtf(v2 + 1e-5f);
                    #pragma unroll
                    for (int ct = 0; ct < 4; ct++)
                        fout[(size_t)row * HID + ct * 16 + (lane & 15)] =
                            (y[ct] - m2) * rv2 * og4[ct] + ob4[ct];
                }
            }
        }
    }
}

extern "C" void kernel_launch(void* const* d_in, const int* in_sizes, int n_in,
                              void* d_out, int out_size, void* d_ws, size_t ws_size,
                              hipStream_t stream) {
    const float* x     = (const float*)d_in[0];
    const int*   ei    = (const int*)d_in[1];
    const float* W_in  = (const float*)d_in[2];
    const float* b_in  = (const float*)d_in[3];
    const float* Wl    = (const float*)d_in[4];
    const float* bl    = (const float*)d_in[5];
    const float* Wr    = (const float*)d_in[6];
    const float* ln_g  = (const float*)d_in[7];
    const float* ln_b  = (const float*)d_in[8];
    const float* out_g = (const float*)d_in[9];
    const float* out_b = (const float*)d_in[10];

    const int N = in_sizes[0] / D_IN;
    const int E = in_sizes[1] / 2;
    const int* src = ei;
    const int* dst = ei + E;
    const int nbuk = (N + BKT_SIZE - 1) >> BKT_BITS;   // 196, must be <= 256

    char* ws = (char*)d_ws;
    size_t off = 0;
    auto take = [&](size_t bytes) {
        char* p = ws + off;
        off += (bytes + 255) & ~(size_t)255;
        return (void*)p;
    };
    u16*      h0      = (u16*)take((size_t)N * HID * 2);
    u16*      h1      = (u16*)take((size_t)N * HID * 2);
    u16*      aggb    = (u16*)take((size_t)N * HID * 2);
    int*      begs    = (int*)take((size_t)N * 4);
    int*      ends    = (int*)take((size_t)N * 4);
    float*    rdeg    = (float*)take((size_t)N * 4);
    int*      ssorted = (int*)take((size_t)nbuk * BKT_CAP * 4);
    unsigned* packedA = (unsigned*)take((size_t)nbuk * BKT_CAP * 4);
    int*      curA    = (int*)take((size_t)nbuk * 4);

    const int NBLK = (N + 255) / 256;

    // 1) input projection (also zeroes curA for step 2)
    proj_mfma<<<NBLK, 256, 0, stream>>>(x, W_in, b_in, h0, N, curA, nbuk);

    // 2) CSR build (single-pass binning into fixed-capacity regions)
    phaseA<<<(E + CHUNK - 1) / CHUNK, 256, 0, stream>>>(src, dst, E, curA, packedA, nbuk);
    phaseB<<<nbuk, 256, 0, stream>>>(packedA, curA, N, ssorted, begs, ends, rdeg);

    // 3) layers (h0 -> h1 -> h0 -> d_out)
    u16* hc = h0;
    u16* hn = h1;
    for (int l = 0; l < NLAYERS; l++) {
        agg_kernel<<<2048, 256, 0, stream>>>(hc, begs, ends, rdeg, ssorted, aggb, N);
        const float* wl = Wl + (size_t)l * HID * HID;
        const float* wr = Wr + (size_t)l * HID * HID;
        const float* bb = bl + (size_t)l * HID;
        const float* lg = ln_g + (size_t)l * HID;
        const float* lb = ln_b + (size_t)l * HID;
        if (l == NLAYERS - 1) {
            layer_mfma<true><<<NBLK, 256, 0, stream>>>(hc, aggb, wl, wr, bb, lg, lb,
                                                       out_g, out_b, nullptr,
                                                       (float*)d_out, N);
        } else {
            layer_mfma<false><<<NBLK, 256, 0, stream>>>(hc, aggb, wl, wr, bb, lg, lb,
                                                        nullptr, nullptr, hn, nullptr, N);
            u16* tmp = hc; hc = hn; hn = tmp;
        }
    }
}

// Round 6
// 264.935 us; speedup vs baseline: 1.0845x; 1.0845x over previous
//
#include <hip/hip_runtime.h>

#define D_IN 384
#define HID 64
#define NLAYERS 3
#define KSTEPS_IN (D_IN / 32)   // 12
#define BKT_BITS 9
#define BKT_SIZE (1 << BKT_BITS)   // 512 nodes per bucket
#define BKT_CAP 12288              // fixed region capacity (mean 8192, +45 sigma)
#define CHUNK 4096                 // edges per phaseA block

typedef __attribute__((ext_vector_type(8))) short bf16x8;
typedef __attribute__((ext_vector_type(4))) float f32x4;
typedef __attribute__((ext_vector_type(4))) unsigned short us4;
typedef unsigned short u16;

__device__ __forceinline__ u16 f2bf(float f) {
    union { float f; unsigned u; } v; v.f = f;
    unsigned u = v.u;
    return (u16)((u + 0x7fffu + ((u >> 16) & 1u)) >> 16);  // RNE
}
__device__ __forceinline__ float bf2f(u16 b) {
    union { unsigned u; float f; } v; v.u = ((unsigned)b) << 16;
    return v.f;
}

// ---------------- input projection: h = relu(x @ W_in + b_in), bf16 out ----------------
__global__ __launch_bounds__(256) void proj_mfma(const float* __restrict__ x,
                                                 const float* __restrict__ W,
                                                 const float* __restrict__ b,
                                                 u16* __restrict__ h, int N,
                                                 int* __restrict__ curA, int nbuk) {
    if (blockIdx.x == 0 && threadIdx.x < (unsigned)nbuk) curA[threadIdx.x] = 0;

    __shared__ u16 sB[KSTEPS_IN * 4 * 64 * 8];   // fragment-ordered W, 48 KB
    const int t = threadIdx.x;
    const int lane = t & 63;
    const int w = t >> 6;

    for (int fi = t; fi < KSTEPS_IN * 4 * 64; fi += 256) {
        int l  = fi & 63;
        int ct = (fi >> 6) & 3;
        int ks = fi >> 8;
        int kbase = ks * 32 + (l >> 4) * 8;
        int col   = ct * 16 + (l & 15);
        u16* d = &sB[(size_t)fi * 8];
        #pragma unroll
        for (int i = 0; i < 8; i++)
            d[i] = f2bf(W[(size_t)(kbase + i) * HID + col]);
    }
    __syncthreads();

    const int row0 = blockIdx.x * 256 + w * 64;
    f32x4 acc[4][4] = {};

    for (int ks = 0; ks < KSTEPS_IN; ks++) {
        bf16x8 a[4];
        #pragma unroll
        for (int rt = 0; rt < 4; rt++) {
            int row = row0 + rt * 16 + (lane & 15);
            if (row >= N) row = N - 1;
            const float* p = &x[(size_t)row * D_IN + ks * 32 + (lane >> 4) * 8];
            f32x4 x0 = *(const f32x4*)p;
            f32x4 x1 = *(const f32x4*)(p + 4);
            bf16x8 aa;
            aa[0] = (short)f2bf(x0[0]); aa[1] = (short)f2bf(x0[1]);
            aa[2] = (short)f2bf(x0[2]); aa[3] = (short)f2bf(x0[3]);
            aa[4] = (short)f2bf(x1[0]); aa[5] = (short)f2bf(x1[1]);
            aa[6] = (short)f2bf(x1[2]); aa[7] = (short)f2bf(x1[3]);
            a[rt] = aa;
        }
        #pragma unroll
        for (int ct = 0; ct < 4; ct++) {
            bf16x8 bb = *(const bf16x8*)&sB[(size_t)((ks * 4 + ct) * 64 + lane) * 8];
            #pragma unroll
            for (int rt = 0; rt < 4; rt++)
                acc[rt][ct] = __builtin_amdgcn_mfma_f32_16x16x32_bf16(a[rt], bb, acc[rt][ct], 0, 0, 0);
        }
    }

    float bias[4];
    #pragma unroll
    for (int ct = 0; ct < 4; ct++) bias[ct] = b[ct * 16 + (lane & 15)];

    #pragma unroll
    for (int rt = 0; rt < 4; rt++) {
        #pragma unroll
        for (int reg = 0; reg < 4; reg++) {
            int row = row0 + rt * 16 + (lane >> 4) * 4 + reg;
            if (row < N) {
                #pragma unroll
                for (int ct = 0; ct < 4; ct++) {
                    int col = ct * 16 + (lane & 15);
                    float v = acc[rt][ct][reg] + bias[ct];
                    h[(size_t)row * HID + col] = f2bf(fmaxf(v, 0.f));
                }
            }
        }
    }
}

// ---------------- CSR build: single-pass binning into fixed-capacity regions --------
__global__ __launch_bounds__(256) void phaseA(const int* __restrict__ src,
                                              const int* __restrict__ dst, int E,
                                              int* __restrict__ curA,
                                              unsigned* __restrict__ packed, int nbuk) {
    __shared__ int hist[256];
    __shared__ int sc[256];
    __shared__ int lbase[256];
    __shared__ int gbase[256];
    __shared__ int lcur[256];
    __shared__ unsigned buf[CHUNK];
    __shared__ unsigned char bid[CHUNK];
    const int t = threadIdx.x;
    const int e0 = blockIdx.x * CHUNK;
    const int cnt = min(CHUNK, E - e0);

    if (t < nbuk) hist[t] = 0;
    __syncthreads();

    unsigned pk[CHUNK / 256];
    int bk[CHUNK / 256];
    #pragma unroll
    for (int j = 0; j < CHUNK / 256; j++) {
        int idx = j * 256 + t;
        if (idx < cnt) {
            int e = e0 + idx;
            int d = dst[e];
            int s = src[e];
            bk[j] = d >> BKT_BITS;
            pk[j] = ((unsigned)s << BKT_BITS) | (unsigned)(d & (BKT_SIZE - 1));
            atomicAdd(&hist[bk[j]], 1);
        } else bk[j] = -1;
    }
    __syncthreads();
    sc[t] = (t < nbuk) ? hist[t] : 0;
    __syncthreads();
    for (int o = 1; o < 256; o <<= 1) {
        int v = (t >= o) ? sc[t - o] : 0;
        __syncthreads();
        sc[t] += v;
        __syncthreads();
    }
    if (t < nbuk) {
        lbase[t] = sc[t] - hist[t];
        lcur[t] = 0;
        gbase[t] = hist[t] ? (t * BKT_CAP + atomicAdd(&curA[t], hist[t])) : 0;
    }
    __syncthreads();
    #pragma unroll
    for (int j = 0; j < CHUNK / 256; j++) {
        if (bk[j] >= 0) {
            int r = atomicAdd(&lcur[bk[j]], 1);
            int slot = lbase[bk[j]] + r;
            buf[slot] = pk[j];
            bid[slot] = (unsigned char)bk[j];
        }
    }
    __syncthreads();
    for (int j = t; j < cnt; j += 256) {
        int b = bid[j];
        packed[gbase[b] + (j - lbase[b])] = buf[j];
    }
}

__global__ __launch_bounds__(256) void phaseB(const unsigned* __restrict__ packed,
                                              const int* __restrict__ curA,
                                              int N,
                                              int* __restrict__ ssorted,
                                              int4* __restrict__ meta) {
    __shared__ int ldeg[BKT_SIZE];
    __shared__ int s[BKT_SIZE];
    __shared__ int lcur[BKT_SIZE];
    const int b = blockIdx.x;
    const int t = threadIdx.x;
    const int rb = b * BKT_CAP;
    const int cnt = curA[b];
    for (int i = t; i < BKT_SIZE; i += 256) ldeg[i] = 0;
    __syncthreads();
    for (int j = t; j < cnt; j += 256)
        atomicAdd(&ldeg[packed[rb + j] & (BKT_SIZE - 1)], 1);
    __syncthreads();
    for (int i = t; i < BKT_SIZE; i += 256) s[i] = ldeg[i];
    __syncthreads();
    for (int o = 1; o < BKT_SIZE; o <<= 1) {
        int v0 = (t >= o) ? s[t - o] : 0;
        int i1 = t + 256;
        int v1 = (i1 >= o) ? s[i1 - o] : 0;
        __syncthreads();
        s[t] += v0;
        s[i1] += v1;
        __syncthreads();
    }
    const int n0 = b << BKT_BITS;
    for (int i = t; i < BKT_SIZE; i += 256) {
        int excl = (i == 0) ? 0 : s[i - 1];
        lcur[i] = excl;
        int n = n0 + i;
        if (n < N) {
            int4 m;
            m.x = rb + excl;
            m.y = rb + excl + ldeg[i];
            m.z = __float_as_int(1.0f / (float)max(ldeg[i], 1));
            m.w = 0;
            meta[n] = m;
        }
    }
    __syncthreads();
    for (int j = t; j < cnt; j += 256) {
        unsigned p = packed[rb + j];
        int l = p & (BKT_SIZE - 1);
        int r = atomicAdd(&lcur[l], 1);
        ssorted[rb + r] = (int)(p >> BKT_BITS);
    }
}

// ---------------- mean aggregation: 4-way unrolled gathers (MLP=4, 16 edges/iter) ----
__global__ __launch_bounds__(256) void agg_kernel(const u16* __restrict__ h,
                                                  const int4* __restrict__ meta,
                                                  const int* __restrict__ ssorted,
                                                  u16* __restrict__ agg, int N) {
    const int lane = threadIdx.x & 63;
    const int wid  = (blockIdx.x * blockDim.x + threadIdx.x) >> 6;
    const int nw   = (gridDim.x * blockDim.x) >> 6;
    const int sub  = lane >> 4;
    const int cg   = lane & 15;
    for (int i = wid; i < N; i += nw) {
        const int4 m = meta[i];
        const int beg = m.x, end = m.y;
        float a0 = 0.f, a1 = 0.f, a2 = 0.f, a3 = 0.f;
        for (int e0 = beg; e0 < end; e0 += 16) {
            int e = e0 + sub;
            int j0 = e, j1 = e + 4, j2 = e + 8, j3 = e + 12;
            float p0 = (j0 < end) ? 1.f : 0.f;
            float p1 = (j1 < end) ? 1.f : 0.f;
            float p2 = (j2 < end) ? 1.f : 0.f;
            float p3 = (j3 < end) ? 1.f : 0.f;
            j0 = min(j0, end - 1); j1 = min(j1, end - 1);
            j2 = min(j2, end - 1); j3 = min(j3, end - 1);
            int s0 = ssorted[j0], s1 = ssorted[j1], s2 = ssorted[j2], s3 = ssorted[j3];
            us4 v0 = *(const us4*)&h[(size_t)s0 * HID + cg * 4];
            us4 v1 = *(const us4*)&h[(size_t)s1 * HID + cg * 4];
            us4 v2 = *(const us4*)&h[(size_t)s2 * HID + cg * 4];
            us4 v3 = *(const us4*)&h[(size_t)s3 * HID + cg * 4];
            a0 += p0 * bf2f(v0[0]) + p1 * bf2f(v1[0]) + p2 * bf2f(v2[0]) + p3 * bf2f(v3[0]);
            a1 += p0 * bf2f(v0[1]) + p1 * bf2f(v1[1]) + p2 * bf2f(v2[1]) + p3 * bf2f(v3[1]);
            a2 += p0 * bf2f(v0[2]) + p1 * bf2f(v1[2]) + p2 * bf2f(v2[2]) + p3 * bf2f(v3[2]);
            a3 += p0 * bf2f(v0[3]) + p1 * bf2f(v1[3]) + p2 * bf2f(v2[3]) + p3 * bf2f(v3[3]);
        }
        #pragma unroll
        for (int mm = 16; mm < 64; mm <<= 1) {
            a0 += __shfl_xor(a0, mm);
            a1 += __shfl_xor(a1, mm);
            a2 += __shfl_xor(a2, mm);
            a3 += __shfl_xor(a3, mm);
        }
        if (lane < 16) {
            float r = __int_as_float(m.z);
            us4 o;
            o[0] = f2bf(a0 * r); o[1] = f2bf(a1 * r);
            o[2] = f2bf(a2 * r); o[3] = f2bf(a3 * r);
            *(us4*)&agg[(size_t)i * HID + cg * 4] = o;
        }
    }
}

// ---------------- fused SAGE layer via MFMA (LAST also applies output LN -> f32) ----
template<bool LAST>
__global__ __launch_bounds__(256) void layer_mfma(const u16* __restrict__ hin,
                                                  const u16* __restrict__ agg,
                                                  const float* __restrict__ Wl,
                                                  const float* __restrict__ Wr,
                                                  const float* __restrict__ bl,
                                                  const float* __restrict__ lng,
                                                  const float* __restrict__ lnb,
                                                  const float* __restrict__ og,
                                                  const float* __restrict__ ob,
                                                  u16* __restrict__ hout,
                                                  float* __restrict__ fout, int N) {
    __shared__ u16 sB[4 * 4 * 64 * 8];
    const int t = threadIdx.x;
    const int lane = t & 63;
    const int w = t >> 6;

    for (int fi = t; fi < 4 * 4 * 64; fi += 256) {
        int l  = fi & 63;
        int ct = (fi >> 6) & 3;
        int ks = fi >> 8;
        int kbase = ks * 32 + (l >> 4) * 8;
        int col   = ct * 16 + (l & 15);
        u16* d = &sB[(size_t)fi * 8];
        #pragma unroll
        for (int i = 0; i < 8; i++) {
            int kk = kbase + i;
            float wv = (kk < 64) ? Wl[(size_t)kk * HID + col]
                                 : Wr[(size_t)(kk - 64) * HID + col];
            d[i] = f2bf(wv);
        }
    }
    __syncthreads();

    const int row0 = blockIdx.x * 256 + w * 64;
    f32x4 acc[4][4] = {};

    #pragma unroll
    for (int ks = 0; ks < 4; ks++) {
        const u16* srcp = (ks < 2) ? agg : hin;
        const int ch0 = (ks & 1) * 32 + (lane >> 4) * 8;
        bf16x8 a[4];
        #pragma unroll
        for (int rt = 0; rt < 4; rt++) {
            int row = row0 + rt * 16 + (lane & 15);
            if (row >= N) row = N - 1;
            a[rt] = *(const bf16x8*)&srcp[(size_t)row * HID + ch0];
        }
        #pragma unroll
        for (int ct = 0; ct < 4; ct++) {
            bf16x8 bb = *(const bf16x8*)&sB[(size_t)((ks * 4 + ct) * 64 + lane) * 8];
            #pragma unroll
            for (int rt = 0; rt < 4; rt++)
                acc[rt][ct] = __builtin_amdgcn_mfma_f32_16x16x32_bf16(a[rt], bb, acc[rt][ct], 0, 0, 0);
        }
    }

    float bias[4], g4[4], be4[4], og4[4], ob4[4];
    #pragma unroll
    for (int ct = 0; ct < 4; ct++) {
        int c = ct * 16 + (lane & 15);
        bias[ct] = bl[c]; g4[ct] = lng[c]; be4[ct] = lnb[c];
        if (LAST) { og4[ct] = og[c]; ob4[ct] = ob[c]; }
    }

    #pragma unroll
    for (int rt = 0; rt < 4; rt++) {
        #pragma unroll
        for (int reg = 0; reg < 4; reg++) {
            int row = row0 + rt * 16 + (lane >> 4) * 4 + reg;
            if (row < N) {
                float v[4];
                float ss = 0.f;
                #pragma unroll
                for (int ct = 0; ct < 4; ct++) {
                    v[ct] = acc[rt][ct][reg] + bias[ct];
                    ss += v[ct] * v[ct];
                }
                #pragma unroll
                for (int m = 1; m < 16; m <<= 1) ss += __shfl_xor(ss, m);
                float rn = rsqrtf(fmaxf(ss, 1e-24f));
                float t4[4];
                float mean = 0.f;
                #pragma unroll
                for (int ct = 0; ct < 4; ct++) {
                    float o = fmaxf(v[ct] * rn, 0.f);
                    float hres = bf2f(hin[(size_t)row * HID + ct * 16 + (lane & 15)]);
                    t4[ct] = o + hres;
                    mean += t4[ct];
                }
                #pragma unroll
                for (int m = 1; m < 16; m <<= 1) mean += __shfl_xor(mean, m);
                mean *= (1.f / 64.f);
                float var = 0.f;
                #pragma unroll
                for (int ct = 0; ct < 4; ct++) {
                    float d = t4[ct] - mean;
                    var += d * d;
                }
                #pragma unroll
                for (int m = 1; m < 16; m <<= 1) var += __shfl_xor(var, m);
                var *= (1.f / 64.f);
                float rv = rsqrtf(var + 1e-5f);
                if (!LAST) {
                    #pragma unroll
                    for (int ct = 0; ct < 4; ct++)
                        hout[(size_t)row * HID + ct * 16 + (lane & 15)] =
                            f2bf((t4[ct] - mean) * rv * g4[ct] + be4[ct]);
                } else {
                    float y[4];
                    float m2 = 0.f;
                    #pragma unroll
                    for (int ct = 0; ct < 4; ct++) {
                        y[ct] = (t4[ct] - mean) * rv * g4[ct] + be4[ct];
                        m2 += y[ct];
                    }
                    #pragma unroll
                    for (int m = 1; m < 16; m <<= 1) m2 += __shfl_xor(m2, m);
                    m2 *= (1.f / 64.f);
                    float v2 = 0.f;
                    #pragma unroll
                    for (int ct = 0; ct < 4; ct++) {
                        float d = y[ct] - m2;
                        v2 += d * d;
                    }
                    #pragma unroll
                    for (int m = 1; m < 16; m <<= 1) v2 += __shfl_xor(v2, m);
                    v2 *= (1.f / 64.f);
                    float rv2 = rsqrtf(v2 + 1e-5f);
                    #pragma unroll
                    for (int ct = 0; ct < 4; ct++)
                        fout[(size_t)row * HID + ct * 16 + (lane & 15)] =
                            (y[ct] - m2) * rv2 * og4[ct] + ob4[ct];
                }
            }
        }
    }
}

extern "C" void kernel_launch(void* const* d_in, const int* in_sizes, int n_in,
                              void* d_out, int out_size, void* d_ws, size_t ws_size,
                              hipStream_t stream) {
    const float* x     = (const float*)d_in[0];
    const int*   ei    = (const int*)d_in[1];
    const float* W_in  = (const float*)d_in[2];
    const float* b_in  = (const float*)d_in[3];
    const float* Wl    = (const float*)d_in[4];
    const float* bl    = (const float*)d_in[5];
    const float* Wr    = (const float*)d_in[6];
    const float* ln_g  = (const float*)d_in[7];
    const float* ln_b  = (const float*)d_in[8];
    const float* out_g = (const float*)d_in[9];
    const float* out_b = (const float*)d_in[10];

    const int N = in_sizes[0] / D_IN;
    const int E = in_sizes[1] / 2;
    const int* src = ei;
    const int* dst = ei + E;
    const int nbuk = (N + BKT_SIZE - 1) >> BKT_BITS;   // 196, must be <= 256

    char* ws = (char*)d_ws;
    size_t off = 0;
    auto take = [&](size_t bytes) {
        char* p = ws + off;
        off += (bytes + 255) & ~(size_t)255;
        return (void*)p;
    };
    u16*      h0      = (u16*)take((size_t)N * HID * 2);
    u16*      h1      = (u16*)take((size_t)N * HID * 2);
    u16*      aggb    = (u16*)take((size_t)N * HID * 2);
    int4*     meta    = (int4*)take((size_t)N * 16);
    int*      ssorted = (int*)take((size_t)nbuk * BKT_CAP * 4);
    unsigned* packedA = (unsigned*)take((size_t)nbuk * BKT_CAP * 4);
    int*      curA    = (int*)take((size_t)nbuk * 4);

    const int NBLK = (N + 255) / 256;

    // 1) input projection (also zeroes curA for step 2)
    proj_mfma<<<NBLK, 256, 0, stream>>>(x, W_in, b_in, h0, N, curA, nbuk);

    // 2) CSR build (single-pass binning into fixed-capacity regions)
    phaseA<<<(E + CHUNK - 1) / CHUNK, 256, 0, stream>>>(src, dst, E, curA, packedA, nbuk);
    phaseB<<<nbuk, 256, 0, stream>>>(packedA, curA, N, ssorted, meta);

    // 3) layers (h0 -> h1 -> h0 -> d_out)
    u16* hc = h0;
    u16* hn = h1;
    for (int l = 0; l < NLAYERS; l++) {
        agg_kernel<<<2048, 256, 0, stream>>>(hc, meta, ssorted, aggb, N);
        const float* wl = Wl + (size_t)l * HID * HID;
        const float* wr = Wr + (size_t)l * HID * HID;
        const float* bb = bl + (size_t)l * HID;
        const float* lg = ln_g + (size_t)l * HID;
        const float* lb = ln_b + (size_t)l * HID;
        if (l == NLAYERS - 1) {
            layer_mfma<true><<<NBLK, 256, 0, stream>>>(hc, aggb, wl, wr, bb, lg, lb,
                                                       out_g, out_b, nullptr,
                                                       (float*)d_out, N);
        } else {
            layer_mfma<false><<<NBLK, 256, 0, stream>>>(hc, aggb, wl, wr, bb, lg, lb,
                                                        nullptr, nullptr, hn, nullptr, N);
            u16* tmp = hc; hc = hn; hn = tmp;
        }
    }
}

// Round 7
// 255.838 us; speedup vs baseline: 1.1231x; 1.0356x over previous
//
#include <hip/hip_runtime.h>

#define D_IN 384
#define HID 64
#define NLAYERS 3
#define KSTEPS_IN (D_IN / 32)   // 12
#define BKT_BITS 9
#define BKT_SIZE (1 << BKT_BITS)   // 512 nodes per bucket
#define BKT_CAP 12288              // region capacity (mean 8192 + pad ~768, +big margin)
#define CHUNK 4096                 // edges per phaseA block

typedef __attribute__((ext_vector_type(8))) short bf16x8;
typedef __attribute__((ext_vector_type(4))) float f32x4;
typedef __attribute__((ext_vector_type(4))) unsigned short us4;
typedef unsigned short u16;

__device__ __forceinline__ u16 f2bf(float f) {
    union { float f; unsigned u; } v; v.f = f;
    unsigned u = v.u;
    return (u16)((u + 0x7fffu + ((u >> 16) & 1u)) >> 16);  // RNE
}
__device__ __forceinline__ float bf2f(u16 b) {
    union { unsigned u; float f; } v; v.u = ((unsigned)b) << 16;
    return v.f;
}

// ---------------- fused: proj (blocks < nprojBlk) || phaseA (remaining blocks) --------
// proj: h = relu(x @ W_in + b_in) -> bf16. phaseA: bin edges into bucket regions.
// Independent data; curA pre-zeroed by hipMemsetAsync.
__global__ __launch_bounds__(256) void proj_phaseA(const float* __restrict__ x,
                                                   const float* __restrict__ W,
                                                   const float* __restrict__ b,
                                                   u16* __restrict__ h, int N, int nprojBlk,
                                                   const int* __restrict__ src,
                                                   const int* __restrict__ dst, int E,
                                                   int* __restrict__ curA,
                                                   unsigned* __restrict__ packed, int nbuk) {
    __shared__ __align__(16) char smem[49152];
    const int t = threadIdx.x;

    if ((int)blockIdx.x < nprojBlk) {
        // ---------------- proj part ----------------
        u16* sB = (u16*)smem;   // fragment-ordered W, 48 KB
        const int lane = t & 63;
        const int w = t >> 6;

        for (int fi = t; fi < KSTEPS_IN * 4 * 64; fi += 256) {
            int l  = fi & 63;
            int ct = (fi >> 6) & 3;
            int ks = fi >> 8;
            int kbase = ks * 32 + (l >> 4) * 8;
            int col   = ct * 16 + (l & 15);
            u16* d = &sB[(size_t)fi * 8];
            #pragma unroll
            for (int i = 0; i < 8; i++)
                d[i] = f2bf(W[(size_t)(kbase + i) * HID + col]);
        }
        __syncthreads();

        const int row0 = blockIdx.x * 256 + w * 64;
        f32x4 acc[4][4] = {};

        for (int ks = 0; ks < KSTEPS_IN; ks++) {
            bf16x8 a[4];
            #pragma unroll
            for (int rt = 0; rt < 4; rt++) {
                int row = row0 + rt * 16 + (lane & 15);
                if (row >= N) row = N - 1;
                const float* p = &x[(size_t)row * D_IN + ks * 32 + (lane >> 4) * 8];
                f32x4 x0 = *(const f32x4*)p;
                f32x4 x1 = *(const f32x4*)(p + 4);
                bf16x8 aa;
                aa[0] = (short)f2bf(x0[0]); aa[1] = (short)f2bf(x0[1]);
                aa[2] = (short)f2bf(x0[2]); aa[3] = (short)f2bf(x0[3]);
                aa[4] = (short)f2bf(x1[0]); aa[5] = (short)f2bf(x1[1]);
                aa[6] = (short)f2bf(x1[2]); aa[7] = (short)f2bf(x1[3]);
                a[rt] = aa;
            }
            #pragma unroll
            for (int ct = 0; ct < 4; ct++) {
                bf16x8 bb = *(const bf16x8*)&sB[(size_t)((ks * 4 + ct) * 64 + lane) * 8];
                #pragma unroll
                for (int rt = 0; rt < 4; rt++)
                    acc[rt][ct] = __builtin_amdgcn_mfma_f32_16x16x32_bf16(a[rt], bb, acc[rt][ct], 0, 0, 0);
            }
        }

        float bias[4];
        #pragma unroll
        for (int ct = 0; ct < 4; ct++) bias[ct] = b[ct * 16 + (lane & 15)];

        #pragma unroll
        for (int rt = 0; rt < 4; rt++) {
            #pragma unroll
            for (int reg = 0; reg < 4; reg++) {
                int row = row0 + rt * 16 + (lane >> 4) * 4 + reg;
                if (row < N) {
                    #pragma unroll
                    for (int ct = 0; ct < 4; ct++) {
                        int col = ct * 16 + (lane & 15);
                        float v = acc[rt][ct][reg] + bias[ct];
                        h[(size_t)row * HID + col] = f2bf(fmaxf(v, 0.f));
                    }
                }
            }
        }
    } else {
        // ---------------- phaseA part ----------------
        int* hist  = (int*)smem;          // 256
        int* sc    = hist + 256;          // 256
        int* lbase = sc + 256;            // 256
        int* gbase = lbase + 256;         // 256
        int* lcur  = gbase + 256;         // 256
        unsigned* buf = (unsigned*)(lcur + 256);          // CHUNK
        unsigned char* bidA = (unsigned char*)(buf + CHUNK); // CHUNK
        const int blk = blockIdx.x - nprojBlk;
        const int e0 = blk * CHUNK;
        const int cnt = min(CHUNK, E - e0);

        if (t < nbuk) hist[t] = 0;
        __syncthreads();

        unsigned pk[CHUNK / 256];
        int bk[CHUNK / 256];
        #pragma unroll
        for (int j = 0; j < CHUNK / 256; j++) {
            int idx = j * 256 + t;
            if (idx < cnt) {
                int e = e0 + idx;
                int d = dst[e];
                int s = src[e];
                bk[j] = d >> BKT_BITS;
                pk[j] = ((unsigned)s << BKT_BITS) | (unsigned)(d & (BKT_SIZE - 1));
                atomicAdd(&hist[bk[j]], 1);
            } else bk[j] = -1;
        }
        __syncthreads();
        sc[t] = (t < nbuk) ? hist[t] : 0;
        __syncthreads();
        for (int o = 1; o < 256; o <<= 1) {
            int v = (t >= o) ? sc[t - o] : 0;
            __syncthreads();
            sc[t] += v;
            __syncthreads();
        }
        if (t < nbuk) {
            lbase[t] = sc[t] - hist[t];
            lcur[t] = 0;
            gbase[t] = hist[t] ? (t * BKT_CAP + atomicAdd(&curA[t], hist[t])) : 0;
        }
        __syncthreads();
        #pragma unroll
        for (int j = 0; j < CHUNK / 256; j++) {
            if (bk[j] >= 0) {
                int r = atomicAdd(&lcur[bk[j]], 1);
                int slot = lbase[bk[j]] + r;
                buf[slot] = pk[j];
                bidA[slot] = (unsigned char)bk[j];
            }
        }
        __syncthreads();
        for (int j = t; j < cnt; j += 256) {
            int bb2 = bidA[j];
            packed[gbase[bb2] + (j - lbase[bb2])] = buf[j];
        }
    }
}

// ---------------- phaseB: per-bucket deg/scan (4-slot aligned regions) + placement ----
__global__ __launch_bounds__(256) void phaseB(const unsigned* __restrict__ packed,
                                              const int* __restrict__ curA,
                                              int N,
                                              int* __restrict__ ssorted,
                                              int4* __restrict__ meta) {
    __shared__ int ldeg[BKT_SIZE];
    __shared__ int s[BKT_SIZE];
    __shared__ int lcur[BKT_SIZE];
    const int b = blockIdx.x;
    const int t = threadIdx.x;
    const int rb = b * BKT_CAP;
    const int cnt = curA[b];
    for (int i = t; i < BKT_SIZE; i += 256) ldeg[i] = 0;
    __syncthreads();
    for (int j = t; j < cnt; j += 256)
        atomicAdd(&ldeg[packed[rb + j] & (BKT_SIZE - 1)], 1);
    __syncthreads();
    // padded scan: regions rounded to 4 slots so each node's edge list is 16B aligned
    for (int i = t; i < BKT_SIZE; i += 256) s[i] = (ldeg[i] + 3) & ~3;
    __syncthreads();
    for (int o = 1; o < BKT_SIZE; o <<= 1) {
        int v0 = (t >= o) ? s[t - o] : 0;
        int i1 = t + 256;
        int v1 = (i1 >= o) ? s[i1 - o] : 0;
        __syncthreads();
        s[t] += v0;
        s[i1] += v1;
        __syncthreads();
    }
    const int n0 = b << BKT_BITS;
    for (int i = t; i < BKT_SIZE; i += 256) {
        int exclPad = (i == 0) ? 0 : s[i - 1];
        lcur[i] = exclPad;
        int n = n0 + i;
        if (n < N) {
            int4 m;
            m.x = rb + exclPad;
            m.y = rb + exclPad + ldeg[i];
            m.z = __float_as_int(1.0f / (float)max(ldeg[i], 1));
            m.w = 0;
            meta[n] = m;
        }
    }
    __syncthreads();
    for (int j = t; j < cnt; j += 256) {
        unsigned p = packed[rb + j];
        int l = p & (BKT_SIZE - 1);
        int r = atomicAdd(&lcur[l], 1);
        ssorted[rb + r] = (int)(p >> BKT_BITS);
    }
}

// ---------------- mean aggregation: contiguous 4-edge chunks per subgroup ----------
// int4 broadcast index load; unpredicated full windows + predicated tail.
__global__ __launch_bounds__(256) void agg_kernel(const u16* __restrict__ h,
                                                  const int4* __restrict__ meta,
                                                  const int* __restrict__ ssorted,
                                                  u16* __restrict__ agg, int N) {
    const int lane = threadIdx.x & 63;
    const int wid  = (blockIdx.x * blockDim.x + threadIdx.x) >> 6;
    const int nw   = (gridDim.x * blockDim.x) >> 6;
    const int sub  = lane >> 4;
    const int cg   = lane & 15;
    for (int i = wid; i < N; i += nw) {
        const int4 m = meta[i];
        const int beg = m.x, end = m.y;
        float a0 = 0.f, a1 = 0.f, a2 = 0.f, a3 = 0.f;
        int e0 = beg;
        for (; e0 + 16 <= end; e0 += 16) {
            const int lb = e0 + sub * 4;            // 16B aligned (beg is 4-slot aligned)
            int4 sidx = *(const int4*)&ssorted[lb]; // broadcast within subgroup
            us4 v0 = *(const us4*)&h[(size_t)sidx.x * HID + cg * 4];
            us4 v1 = *(const us4*)&h[(size_t)sidx.y * HID + cg * 4];
            us4 v2 = *(const us4*)&h[(size_t)sidx.z * HID + cg * 4];
            us4 v3 = *(const us4*)&h[(size_t)sidx.w * HID + cg * 4];
            a0 += bf2f(v0[0]) + bf2f(v1[0]) + bf2f(v2[0]) + bf2f(v3[0]);
            a1 += bf2f(v0[1]) + bf2f(v1[1]) + bf2f(v2[1]) + bf2f(v3[1]);
            a2 += bf2f(v0[2]) + bf2f(v1[2]) + bf2f(v2[2]) + bf2f(v3[2]);
            a3 += bf2f(v0[3]) + bf2f(v1[3]) + bf2f(v2[3]) + bf2f(v3[3]);
        }
        if (e0 < end) {
            const int lb = e0 + sub * 4;
            int4 sidx = *(const int4*)&ssorted[lb]; // pad slots may be garbage -> clamp
            int j0 = lb, j1 = lb + 1, j2 = lb + 2, j3 = lb + 3;
            float p0 = (j0 < end) ? 1.f : 0.f;
            float p1 = (j1 < end) ? 1.f : 0.f;
            float p2 = (j2 < end) ? 1.f : 0.f;
            float p3 = (j3 < end) ? 1.f : 0.f;
            int s0 = (j0 < end) ? sidx.x : 0;
            int s1 = (j1 < end) ? sidx.y : 0;
            int s2 = (j2 < end) ? sidx.z : 0;
            int s3 = (j3 < end) ? sidx.w : 0;
            us4 v0 = *(const us4*)&h[(size_t)s0 * HID + cg * 4];
            us4 v1 = *(const us4*)&h[(size_t)s1 * HID + cg * 4];
            us4 v2 = *(const us4*)&h[(size_t)s2 * HID + cg * 4];
            us4 v3 = *(const us4*)&h[(size_t)s3 * HID + cg * 4];
            a0 += p0 * bf2f(v0[0]) + p1 * bf2f(v1[0]) + p2 * bf2f(v2[0]) + p3 * bf2f(v3[0]);
            a1 += p0 * bf2f(v0[1]) + p1 * bf2f(v1[1]) + p2 * bf2f(v2[1]) + p3 * bf2f(v3[1]);
            a2 += p0 * bf2f(v0[2]) + p1 * bf2f(v1[2]) + p2 * bf2f(v2[2]) + p3 * bf2f(v3[2]);
            a3 += p0 * bf2f(v0[3]) + p1 * bf2f(v1[3]) + p2 * bf2f(v2[3]) + p3 * bf2f(v3[3]);
        }
        #pragma unroll
        for (int mm = 16; mm < 64; mm <<= 1) {
            a0 += __shfl_xor(a0, mm);
            a1 += __shfl_xor(a1, mm);
            a2 += __shfl_xor(a2, mm);
            a3 += __shfl_xor(a3, mm);
        }
        if (lane < 16) {
            float r = __int_as_float(m.z);
            us4 o;
            o[0] = f2bf(a0 * r); o[1] = f2bf(a1 * r);
            o[2] = f2bf(a2 * r); o[3] = f2bf(a3 * r);
            *(us4*)&agg[(size_t)i * HID + cg * 4] = o;
        }
    }
}

// ---------------- fused SAGE layer via MFMA (LAST also applies output LN -> f32) ----
template<bool LAST>
__global__ __launch_bounds__(256) void layer_mfma(const u16* __restrict__ hin,
                                                  const u16* __restrict__ agg,
                                                  const float* __restrict__ Wl,
                                                  const float* __restrict__ Wr,
                                                  const float* __restrict__ bl,
                                                  const float* __restrict__ lng,
                                                  const float* __restrict__ lnb,
                                                  const float* __restrict__ og,
                                                  const float* __restrict__ ob,
                                                  u16* __restrict__ hout,
                                                  float* __restrict__ fout, int N) {
    __shared__ u16 sB[4 * 4 * 64 * 8];
    const int t = threadIdx.x;
    const int lane = t & 63;
    const int w = t >> 6;

    for (int fi = t; fi < 4 * 4 * 64; fi += 256) {
        int l  = fi & 63;
        int ct = (fi >> 6) & 3;
        int ks = fi >> 8;
        int kbase = ks * 32 + (l >> 4) * 8;
        int col   = ct * 16 + (l & 15);
        u16* d = &sB[(size_t)fi * 8];
        #pragma unroll
        for (int i = 0; i < 8; i++) {
            int kk = kbase + i;
            float wv = (kk < 64) ? Wl[(size_t)kk * HID + col]
                                 : Wr[(size_t)(kk - 64) * HID + col];
            d[i] = f2bf(wv);
        }
    }
    __syncthreads();

    const int row0 = blockIdx.x * 256 + w * 64;
    f32x4 acc[4][4] = {};

    #pragma unroll
    for (int ks = 0; ks < 4; ks++) {
        const u16* srcp = (ks < 2) ? agg : hin;
        const int ch0 = (ks & 1) * 32 + (lane >> 4) * 8;
        bf16x8 a[4];
        #pragma unroll
        for (int rt = 0; rt < 4; rt++) {
            int row = row0 + rt * 16 + (lane & 15);
            if (row >= N) row = N - 1;
            a[rt] = *(const bf16x8*)&srcp[(size_t)row * HID + ch0];
        }
        #pragma unroll
        for (int ct = 0; ct < 4; ct++) {
            bf16x8 bb = *(const bf16x8*)&sB[(size_t)((ks * 4 + ct) * 64 + lane) * 8];
            #pragma unroll
            for (int rt = 0; rt < 4; rt++)
                acc[rt][ct] = __builtin_amdgcn_mfma_f32_16x16x32_bf16(a[rt], bb, acc[rt][ct], 0, 0, 0);
        }
    }

    float bias[4], g4[4], be4[4], og4[4], ob4[4];
    #pragma unroll
    for (int ct = 0; ct < 4; ct++) {
        int c = ct * 16 + (lane & 15);
        bias[ct] = bl[c]; g4[ct] = lng[c]; be4[ct] = lnb[c];
        if (LAST) { og4[ct] = og[c]; ob4[ct] = ob[c]; }
    }

    #pragma unroll
    for (int rt = 0; rt < 4; rt++) {
        #pragma unroll
        for (int reg = 0; reg < 4; reg++) {
            int row = row0 + rt * 16 + (lane >> 4) * 4 + reg;
            if (row < N) {
                float v[4];
                float ss = 0.f;
                #pragma unroll
                for (int ct = 0; ct < 4; ct++) {
                    v[ct] = acc[rt][ct][reg] + bias[ct];
                    ss += v[ct] * v[ct];
                }
                #pragma unroll
                for (int m = 1; m < 16; m <<= 1) ss += __shfl_xor(ss, m);
                float rn = rsqrtf(fmaxf(ss, 1e-24f));
                float t4[4];
                float mean = 0.f;
                #pragma unroll
                for (int ct = 0; ct < 4; ct++) {
                    float o = fmaxf(v[ct] * rn, 0.f);
                    float hres = bf2f(hin[(size_t)row * HID + ct * 16 + (lane & 15)]);
                    t4[ct] = o + hres;
                    mean += t4[ct];
                }
                #pragma unroll
                for (int m = 1; m < 16; m <<= 1) mean += __shfl_xor(mean, m);
                mean *= (1.f / 64.f);
                float var = 0.f;
                #pragma unroll
                for (int ct = 0; ct < 4; ct++) {
                    float d = t4[ct] - mean;
                    var += d * d;
                }
                #pragma unroll
                for (int m = 1; m < 16; m <<= 1) var += __shfl_xor(var, m);
                var *= (1.f / 64.f);
                float rv = rsqrtf(var + 1e-5f);
                if (!LAST) {
                    #pragma unroll
                    for (int ct = 0; ct < 4; ct++)
                        hout[(size_t)row * HID + ct * 16 + (lane & 15)] =
                            f2bf((t4[ct] - mean) * rv * g4[ct] + be4[ct]);
                } else {
                    float y[4];
                    float m2 = 0.f;
                    #pragma unroll
                    for (int ct = 0; ct < 4; ct++) {
                        y[ct] = (t4[ct] - mean) * rv * g4[ct] + be4[ct];
                        m2 += y[ct];
                    }
                    #pragma unroll
                    for (int m = 1; m < 16; m <<= 1) m2 += __shfl_xor(m2, m);
                    m2 *= (1.f / 64.f);
                    float v2 = 0.f;
                    #pragma unroll
                    for (int ct = 0; ct < 4; ct++) {
                        float d = y[ct] - m2;
                        v2 += d * d;
                    }
                    #pragma unroll
                    for (int m = 1; m < 16; m <<= 1) v2 += __shfl_xor(v2, m);
                    v2 *= (1.f / 64.f);
                    float rv2 = rsqrtf(v2 + 1e-5f);
                    #pragma unroll
                    for (int ct = 0; ct < 4; ct++)
                        fout[(size_t)row * HID + ct * 16 + (lane & 15)] =
                            (y[ct] - m2) * rv2 * og4[ct] + ob4[ct];
                }
            }
        }
    }
}

extern "C" void kernel_launch(void* const* d_in, const int* in_sizes, int n_in,
                              void* d_out, int out_size, void* d_ws, size_t ws_size,
                              hipStream_t stream) {
    const float* x     = (const float*)d_in[0];
    const int*   ei    = (const int*)d_in[1];
    const float* W_in  = (const float*)d_in[2];
    const float* b_in  = (const float*)d_in[3];
    const float* Wl    = (const float*)d_in[4];
    const float* bl    = (const float*)d_in[5];
    const float* Wr    = (const float*)d_in[6];
    const float* ln_g  = (const float*)d_in[7];
    const float* ln_b  = (const float*)d_in[8];
    const float* out_g = (const float*)d_in[9];
    const float* out_b = (const float*)d_in[10];

    const int N = in_sizes[0] / D_IN;
    const int E = in_sizes[1] / 2;
    const int* src = ei;
    const int* dst = ei + E;
    const int nbuk = (N + BKT_SIZE - 1) >> BKT_BITS;   // 196, must be <= 256

    char* ws = (char*)d_ws;
    size_t off = 0;
    auto take = [&](size_t bytes) {
        char* p = ws + off;
        off += (bytes + 255) & ~(size_t)255;
        return (void*)p;
    };
    u16*      h0      = (u16*)take((size_t)N * HID * 2);
    u16*      h1      = (u16*)take((size_t)N * HID * 2);
    u16*      aggb    = (u16*)take((size_t)N * HID * 2);
    int4*     meta    = (int4*)take((size_t)N * 16);
    int*      ssorted = (int*)take(((size_t)nbuk * BKT_CAP + 64) * 4);
    unsigned* packedA = (unsigned*)take(((size_t)nbuk * BKT_CAP + 64) * 4);
    int*      curA    = (int*)take((size_t)nbuk * 4);

    const int NBLK = (N + 255) / 256;
    const int ABLK = (E + CHUNK - 1) / CHUNK;

    // 1) zero bucket cursors (tiny), then fused proj || phaseA (independent work)
    hipMemsetAsync(curA, 0, (size_t)nbuk * 4, stream);
    proj_phaseA<<<NBLK + ABLK, 256, 0, stream>>>(x, W_in, b_in, h0, N, NBLK,
                                                 src, dst, E, curA, packedA, nbuk);

    // 2) per-bucket CSR finalize (aligned regions)
    phaseB<<<nbuk, 256, 0, stream>>>(packedA, curA, N, ssorted, meta);

    // 3) layers (h0 -> h1 -> h0 -> d_out)
    u16* hc = h0;
    u16* hn = h1;
    for (int l = 0; l < NLAYERS; l++) {
        agg_kernel<<<2048, 256, 0, stream>>>(hc, meta, ssorted, aggb, N);
        const float* wl = Wl + (size_t)l * HID * HID;
        const float* wr = Wr + (size_t)l * HID * HID;
        const float* bb = bl + (size_t)l * HID;
        const float* lg = ln_g + (size_t)l * HID;
        const float* lb = ln_b + (size_t)l * HID;
        if (l == NLAYERS - 1) {
            layer_mfma<true><<<NBLK, 256, 0, stream>>>(hc, aggb, wl, wr, bb, lg, lb,
                                                       out_g, out_b, nullptr,
                                                       (float*)d_out, N);
        } else {
            layer_mfma<false><<<NBLK, 256, 0, stream>>>(hc, aggb, wl, wr, bb, lg, lb,
                                                        nullptr, nullptr, hn, nullptr, N);
            u16* tmp = hc; hc = hn; hn = tmp;
        }
    }
}

// Round 8
// 246.640 us; speedup vs baseline: 1.1650x; 1.0373x over previous
//
#include <hip/hip_runtime.h>

#define D_IN 384
#define HID 64
#define NLAYERS 3
#define KSTEPS_IN (D_IN / 32)   // 12
#define BKT_BITS 9
#define BKT_SIZE (1 << BKT_BITS)   // 512 nodes per bucket
#define BKT_CAP 12288              // region capacity (mean 8192 + pad, big margin)
#define CHUNK 4096                 // edges per phaseA block

typedef __attribute__((ext_vector_type(8))) short bf16x8;
typedef __attribute__((ext_vector_type(4))) float f32x4;
typedef __attribute__((ext_vector_type(4))) unsigned short us4;
typedef unsigned short u16;
typedef unsigned char u8;

__device__ __forceinline__ u16 f2bf(float f) {
    union { float f; unsigned u; } v; v.f = f;
    unsigned u = v.u;
    return (u16)((u + 0x7fffu + ((u >> 16) & 1u)) >> 16);  // RNE
}
__device__ __forceinline__ float bf2f(u16 b) {
    union { unsigned u; float f; } v; v.u = ((unsigned)b) << 16;
    return v.f;
}
// fp8 e4m3 encode via HW packed cvt (self-consistent with HW decode)
__device__ __forceinline__ u8 f2fp8(float f) {
    unsigned v = __builtin_amdgcn_cvt_pk_fp8_f32(f, f, 0, false);
    return (u8)(v & 0xffu);
}

// ---------------- fused: proj (blocks < nprojBlk) || phaseA (remaining blocks) --------
__global__ __launch_bounds__(256) void proj_phaseA(const float* __restrict__ x,
                                                   const float* __restrict__ W,
                                                   const float* __restrict__ b,
                                                   u16* __restrict__ h,
                                                   u8* __restrict__ hq, int N, int nprojBlk,
                                                   const int* __restrict__ src,
                                                   const int* __restrict__ dst, int E,
                                                   int* __restrict__ curA,
                                                   unsigned* __restrict__ packed, int nbuk) {
    __shared__ __align__(16) char smem[49152];
    const int t = threadIdx.x;

    if ((int)blockIdx.x < nprojBlk) {
        // ---------------- proj part ----------------
        u16* sB = (u16*)smem;   // fragment-ordered W, 48 KB
        const int lane = t & 63;
        const int w = t >> 6;

        for (int fi = t; fi < KSTEPS_IN * 4 * 64; fi += 256) {
            int l  = fi & 63;
            int ct = (fi >> 6) & 3;
            int ks = fi >> 8;
            int kbase = ks * 32 + (l >> 4) * 8;
            int col   = ct * 16 + (l & 15);
            u16* d = &sB[(size_t)fi * 8];
            #pragma unroll
            for (int i = 0; i < 8; i++)
                d[i] = f2bf(W[(size_t)(kbase + i) * HID + col]);
        }
        __syncthreads();

        const int row0 = blockIdx.x * 256 + w * 64;
        f32x4 acc[4][4] = {};

        for (int ks = 0; ks < KSTEPS_IN; ks++) {
            bf16x8 a[4];
            #pragma unroll
            for (int rt = 0; rt < 4; rt++) {
                int row = row0 + rt * 16 + (lane & 15);
                if (row >= N) row = N - 1;
                const float* p = &x[(size_t)row * D_IN + ks * 32 + (lane >> 4) * 8];
                f32x4 x0 = *(const f32x4*)p;
                f32x4 x1 = *(const f32x4*)(p + 4);
                bf16x8 aa;
                aa[0] = (short)f2bf(x0[0]); aa[1] = (short)f2bf(x0[1]);
                aa[2] = (short)f2bf(x0[2]); aa[3] = (short)f2bf(x0[3]);
                aa[4] = (short)f2bf(x1[0]); aa[5] = (short)f2bf(x1[1]);
                aa[6] = (short)f2bf(x1[2]); aa[7] = (short)f2bf(x1[3]);
                a[rt] = aa;
            }
            #pragma unroll
            for (int ct = 0; ct < 4; ct++) {
                bf16x8 bb = *(const bf16x8*)&sB[(size_t)((ks * 4 + ct) * 64 + lane) * 8];
                #pragma unroll
                for (int rt = 0; rt < 4; rt++)
                    acc[rt][ct] = __builtin_amdgcn_mfma_f32_16x16x32_bf16(a[rt], bb, acc[rt][ct], 0, 0, 0);
            }
        }

        float bias[4];
        #pragma unroll
        for (int ct = 0; ct < 4; ct++) bias[ct] = b[ct * 16 + (lane & 15)];

        #pragma unroll
        for (int rt = 0; rt < 4; rt++) {
            #pragma unroll
            for (int reg = 0; reg < 4; reg++) {
                int row = row0 + rt * 16 + (lane >> 4) * 4 + reg;
                if (row < N) {
                    #pragma unroll
                    for (int ct = 0; ct < 4; ct++) {
                        int col = ct * 16 + (lane & 15);
                        float v = fmaxf(acc[rt][ct][reg] + bias[ct], 0.f);
                        h[(size_t)row * HID + col] = f2bf(v);
                        hq[(size_t)row * HID + col] = f2fp8(v);
                    }
                }
            }
        }
    } else {
        // ---------------- phaseA part ----------------
        int* hist  = (int*)smem;
        int* sc    = hist + 256;
        int* lbase = sc + 256;
        int* gbase = lbase + 256;
        int* lcur  = gbase + 256;
        unsigned* buf = (unsigned*)(lcur + 256);
        unsigned char* bidA = (unsigned char*)(buf + CHUNK);
        const int blk = blockIdx.x - nprojBlk;
        const int e0 = blk * CHUNK;
        const int cnt = min(CHUNK, E - e0);

        if (t < nbuk) hist[t] = 0;
        __syncthreads();

        unsigned pk[CHUNK / 256];
        int bk[CHUNK / 256];
        #pragma unroll
        for (int j = 0; j < CHUNK / 256; j++) {
            int idx = j * 256 + t;
            if (idx < cnt) {
                int e = e0 + idx;
                int d = dst[e];
                int s = src[e];
                bk[j] = d >> BKT_BITS;
                pk[j] = ((unsigned)s << BKT_BITS) | (unsigned)(d & (BKT_SIZE - 1));
                atomicAdd(&hist[bk[j]], 1);
            } else bk[j] = -1;
        }
        __syncthreads();
        sc[t] = (t < nbuk) ? hist[t] : 0;
        __syncthreads();
        for (int o = 1; o < 256; o <<= 1) {
            int v = (t >= o) ? sc[t - o] : 0;
            __syncthreads();
            sc[t] += v;
            __syncthreads();
        }
        if (t < nbuk) {
            lbase[t] = sc[t] - hist[t];
            lcur[t] = 0;
            gbase[t] = hist[t] ? (t * BKT_CAP + atomicAdd(&curA[t], hist[t])) : 0;
        }
        __syncthreads();
        #pragma unroll
        for (int j = 0; j < CHUNK / 256; j++) {
            if (bk[j] >= 0) {
                int r = atomicAdd(&lcur[bk[j]], 1);
                int slot = lbase[bk[j]] + r;
                buf[slot] = pk[j];
                bidA[slot] = (unsigned char)bk[j];
            }
        }
        __syncthreads();
        for (int j = t; j < cnt; j += 256) {
            int bb2 = bidA[j];
            packed[gbase[bb2] + (j - lbase[bb2])] = buf[j];
        }
    }
}

// ---------------- phaseB: per-bucket deg/scan (4-slot aligned regions) + placement ----
__global__ __launch_bounds__(256) void phaseB(const unsigned* __restrict__ packed,
                                              const int* __restrict__ curA,
                                              int N,
                                              int* __restrict__ ssorted,
                                              int4* __restrict__ meta) {
    __shared__ int ldeg[BKT_SIZE];
    __shared__ int s[BKT_SIZE];
    __shared__ int lcur[BKT_SIZE];
    const int b = blockIdx.x;
    const int t = threadIdx.x;
    const int rb = b * BKT_CAP;
    const int cnt = curA[b];
    for (int i = t; i < BKT_SIZE; i += 256) ldeg[i] = 0;
    __syncthreads();
    for (int j = t; j < cnt; j += 256)
        atomicAdd(&ldeg[packed[rb + j] & (BKT_SIZE - 1)], 1);
    __syncthreads();
    for (int i = t; i < BKT_SIZE; i += 256) s[i] = (ldeg[i] + 3) & ~3;
    __syncthreads();
    for (int o = 1; o < BKT_SIZE; o <<= 1) {
        int v0 = (t >= o) ? s[t - o] : 0;
        int i1 = t + 256;
        int v1 = (i1 >= o) ? s[i1 - o] : 0;
        __syncthreads();
        s[t] += v0;
        s[i1] += v1;
        __syncthreads();
    }
    const int n0 = b << BKT_BITS;
    for (int i = t; i < BKT_SIZE; i += 256) {
        int exclPad = (i == 0) ? 0 : s[i - 1];
        lcur[i] = exclPad;
        int n = n0 + i;
        if (n < N) {
            int4 m;
            m.x = rb + exclPad;
            m.y = rb + exclPad + ldeg[i];
            m.z = __float_as_int(1.0f / (float)max(ldeg[i], 1));
            m.w = 0;
            meta[n] = m;
        }
    }
    __syncthreads();
    for (int j = t; j < cnt; j += 256) {
        unsigned p = packed[rb + j];
        int l = p & (BKT_SIZE - 1);
        int r = atomicAdd(&lcur[l], 1);
        ssorted[rb + r] = (int)(p >> BKT_BITS);
    }
}

// ---------------- mean aggregation: fp8 gathers (64 B/edge), HW cvt decode ----------
__global__ __launch_bounds__(256) void agg_kernel(const u8* __restrict__ hq,
                                                  const int4* __restrict__ meta,
                                                  const int* __restrict__ ssorted,
                                                  u16* __restrict__ agg, int N) {
    const int lane = threadIdx.x & 63;
    const int wid  = (blockIdx.x * blockDim.x + threadIdx.x) >> 6;
    const int nw   = (gridDim.x * blockDim.x) >> 6;
    const int sub  = lane >> 4;
    const int cg   = lane & 15;
    for (int i = wid; i < N; i += nw) {
        const int4 m = meta[i];
        const int beg = m.x, end = m.y;
        float a0 = 0.f, a1 = 0.f, a2 = 0.f, a3 = 0.f;
        int e0 = beg;
        for (; e0 + 16 <= end; e0 += 16) {
            const int lb = e0 + sub * 4;
            int4 sidx = *(const int4*)&ssorted[lb];
            unsigned q0 = *(const unsigned*)&hq[(size_t)sidx.x * HID + cg * 4];
            unsigned q1 = *(const unsigned*)&hq[(size_t)sidx.y * HID + cg * 4];
            unsigned q2 = *(const unsigned*)&hq[(size_t)sidx.z * HID + cg * 4];
            unsigned q3 = *(const unsigned*)&hq[(size_t)sidx.w * HID + cg * 4];
            a0 += __builtin_amdgcn_cvt_f32_fp8(q0, 0) + __builtin_amdgcn_cvt_f32_fp8(q1, 0)
                + __builtin_amdgcn_cvt_f32_fp8(q2, 0) + __builtin_amdgcn_cvt_f32_fp8(q3, 0);
            a1 += __builtin_amdgcn_cvt_f32_fp8(q0, 1) + __builtin_amdgcn_cvt_f32_fp8(q1, 1)
                + __builtin_amdgcn_cvt_f32_fp8(q2, 1) + __builtin_amdgcn_cvt_f32_fp8(q3, 1);
            a2 += __builtin_amdgcn_cvt_f32_fp8(q0, 2) + __builtin_amdgcn_cvt_f32_fp8(q1, 2)
                + __builtin_amdgcn_cvt_f32_fp8(q2, 2) + __builtin_amdgcn_cvt_f32_fp8(q3, 2);
            a3 += __builtin_amdgcn_cvt_f32_fp8(q0, 3) + __builtin_amdgcn_cvt_f32_fp8(q1, 3)
                + __builtin_amdgcn_cvt_f32_fp8(q2, 3) + __builtin_amdgcn_cvt_f32_fp8(q3, 3);
        }
        if (e0 < end) {
            const int lb = e0 + sub * 4;
            int4 sidx = *(const int4*)&ssorted[lb];   // pad slots may be garbage -> clamp
            int j0 = lb, j1 = lb + 1, j2 = lb + 2, j3 = lb + 3;
            float p0 = (j0 < end) ? 1.f : 0.f;
            float p1 = (j1 < end) ? 1.f : 0.f;
            float p2 = (j2 < end) ? 1.f : 0.f;
            float p3 = (j3 < end) ? 1.f : 0.f;
            int s0 = (j0 < end) ? sidx.x : 0;
            int s1 = (j1 < end) ? sidx.y : 0;
            int s2 = (j2 < end) ? sidx.z : 0;
            int s3 = (j3 < end) ? sidx.w : 0;
            unsigned q0 = *(const unsigned*)&hq[(size_t)s0 * HID + cg * 4];
            unsigned q1 = *(const unsigned*)&hq[(size_t)s1 * HID + cg * 4];
            unsigned q2 = *(const unsigned*)&hq[(size_t)s2 * HID + cg * 4];
            unsigned q3 = *(const unsigned*)&hq[(size_t)s3 * HID + cg * 4];
            a0 += p0 * __builtin_amdgcn_cvt_f32_fp8(q0, 0) + p1 * __builtin_amdgcn_cvt_f32_fp8(q1, 0)
                + p2 * __builtin_amdgcn_cvt_f32_fp8(q2, 0) + p3 * __builtin_amdgcn_cvt_f32_fp8(q3, 0);
            a1 += p0 * __builtin_amdgcn_cvt_f32_fp8(q0, 1) + p1 * __builtin_amdgcn_cvt_f32_fp8(q1, 1)
                + p2 * __builtin_amdgcn_cvt_f32_fp8(q2, 1) + p3 * __builtin_amdgcn_cvt_f32_fp8(q3, 1);
            a2 += p0 * __builtin_amdgcn_cvt_f32_fp8(q0, 2) + p1 * __builtin_amdgcn_cvt_f32_fp8(q1, 2)
                + p2 * __builtin_amdgcn_cvt_f32_fp8(q2, 2) + p3 * __builtin_amdgcn_cvt_f32_fp8(q3, 2);
            a3 += p0 * __builtin_amdgcn_cvt_f32_fp8(q0, 3) + p1 * __builtin_amdgcn_cvt_f32_fp8(q1, 3)
                + p2 * __builtin_amdgcn_cvt_f32_fp8(q2, 3) + p3 * __builtin_amdgcn_cvt_f32_fp8(q3, 3);
        }
        #pragma unroll
        for (int mm = 16; mm < 64; mm <<= 1) {
            a0 += __shfl_xor(a0, mm);
            a1 += __shfl_xor(a1, mm);
            a2 += __shfl_xor(a2, mm);
            a3 += __shfl_xor(a3, mm);
        }
        if (lane < 16) {
            float r = __int_as_float(m.z);
            us4 o;
            o[0] = f2bf(a0 * r); o[1] = f2bf(a1 * r);
            o[2] = f2bf(a2 * r); o[3] = f2bf(a3 * r);
            *(us4*)&agg[(size_t)i * HID + cg * 4] = o;
        }
    }
}

// ---------------- fused SAGE layer via MFMA (LAST also applies output LN -> f32) ----
template<bool LAST>
__global__ __launch_bounds__(256) void layer_mfma(const u16* __restrict__ hin,
                                                  const u16* __restrict__ agg,
                                                  const float* __restrict__ Wl,
                                                  const float* __restrict__ Wr,
                                                  const float* __restrict__ bl,
                                                  const float* __restrict__ lng,
                                                  const float* __restrict__ lnb,
                                                  const float* __restrict__ og,
                                                  const float* __restrict__ ob,
                                                  u16* __restrict__ hout,
                                                  u8* __restrict__ hqout,
                                                  float* __restrict__ fout, int N) {
    __shared__ u16 sB[4 * 4 * 64 * 8];
    const int t = threadIdx.x;
    const int lane = t & 63;
    const int w = t >> 6;

    for (int fi = t; fi < 4 * 4 * 64; fi += 256) {
        int l  = fi & 63;
        int ct = (fi >> 6) & 3;
        int ks = fi >> 8;
        int kbase = ks * 32 + (l >> 4) * 8;
        int col   = ct * 16 + (l & 15);
        u16* d = &sB[(size_t)fi * 8];
        #pragma unroll
        for (int i = 0; i < 8; i++) {
            int kk = kbase + i;
            float wv = (kk < 64) ? Wl[(size_t)kk * HID + col]
                                 : Wr[(size_t)(kk - 64) * HID + col];
            d[i] = f2bf(wv);
        }
    }
    __syncthreads();

    const int row0 = blockIdx.x * 256 + w * 64;
    f32x4 acc[4][4] = {};

    #pragma unroll
    for (int ks = 0; ks < 4; ks++) {
        const u16* srcp = (ks < 2) ? agg : hin;
        const int ch0 = (ks & 1) * 32 + (lane >> 4) * 8;
        bf16x8 a[4];
        #pragma unroll
        for (int rt = 0; rt < 4; rt++) {
            int row = row0 + rt * 16 + (lane & 15);
            if (row >= N) row = N - 1;
            a[rt] = *(const bf16x8*)&srcp[(size_t)row * HID + ch0];
        }
        #pragma unroll
        for (int ct = 0; ct < 4; ct++) {
            bf16x8 bb = *(const bf16x8*)&sB[(size_t)((ks * 4 + ct) * 64 + lane) * 8];
            #pragma unroll
            for (int rt = 0; rt < 4; rt++)
                acc[rt][ct] = __builtin_amdgcn_mfma_f32_16x16x32_bf16(a[rt], bb, acc[rt][ct], 0, 0, 0);
        }
    }

    float bias[4], g4[4], be4[4], og4[4], ob4[4];
    #pragma unroll
    for (int ct = 0; ct < 4; ct++) {
        int c = ct * 16 + (lane & 15);
        bias[ct] = bl[c]; g4[ct] = lng[c]; be4[ct] = lnb[c];
        if (LAST) { og4[ct] = og[c]; ob4[ct] = ob[c]; }
    }

    #pragma unroll
    for (int rt = 0; rt < 4; rt++) {
        #pragma unroll
        for (int reg = 0; reg < 4; reg++) {
            int row = row0 + rt * 16 + (lane >> 4) * 4 + reg;
            if (row < N) {
                float v[4];
                float ss = 0.f;
                #pragma unroll
                for (int ct = 0; ct < 4; ct++) {
                    v[ct] = acc[rt][ct][reg] + bias[ct];
                    ss += v[ct] * v[ct];
                }
                #pragma unroll
                for (int m = 1; m < 16; m <<= 1) ss += __shfl_xor(ss, m);
                float rn = rsqrtf(fmaxf(ss, 1e-24f));
                float t4[4];
                float mean = 0.f;
                #pragma unroll
                for (int ct = 0; ct < 4; ct++) {
                    float o = fmaxf(v[ct] * rn, 0.f);
                    float hres = bf2f(hin[(size_t)row * HID + ct * 16 + (lane & 15)]);
                    t4[ct] = o + hres;
                    mean += t4[ct];
                }
                #pragma unroll
                for (int m = 1; m < 16; m <<= 1) mean += __shfl_xor(mean, m);
                mean *= (1.f / 64.f);
                float var = 0.f;
                #pragma unroll
                for (int ct = 0; ct < 4; ct++) {
                    float d = t4[ct] - mean;
                    var += d * d;
                }
                #pragma unroll
                for (int m = 1; m < 16; m <<= 1) var += __shfl_xor(var, m);
                var *= (1.f / 64.f);
                float rv = rsqrtf(var + 1e-5f);
                if (!LAST) {
                    #pragma unroll
                    for (int ct = 0; ct < 4; ct++) {
                        float val = (t4[ct] - mean) * rv * g4[ct] + be4[ct];
                        int c = ct * 16 + (lane & 15);
                        hout[(size_t)row * HID + c] = f2bf(val);
                        hqout[(size_t)row * HID + c] = f2fp8(val);
                    }
                } else {
                    float y[4];
                    float m2 = 0.f;
                    #pragma unroll
                    for (int ct = 0; ct < 4; ct++) {
                        y[ct] = (t4[ct] - mean) * rv * g4[ct] + be4[ct];
                        m2 += y[ct];
                    }
                    #pragma unroll
                    for (int m = 1; m < 16; m <<= 1) m2 += __shfl_xor(m2, m);
                    m2 *= (1.f / 64.f);
                    float v2 = 0.f;
                    #pragma unroll
                    for (int ct = 0; ct < 4; ct++) {
                        float d = y[ct] - m2;
                        v2 += d * d;
                    }
                    #pragma unroll
                    for (int m = 1; m < 16; m <<= 1) v2 += __shfl_xor(v2, m);
                    v2 *= (1.f / 64.f);
                    float rv2 = rsqrtf(v2 + 1e-5f);
                    #pragma unroll
                    for (int ct = 0; ct < 4; ct++)
                        fout[(size_t)row * HID + ct * 16 + (lane & 15)] =
                            (y[ct] - m2) * rv2 * og4[ct] + ob4[ct];
                }
            }
        }
    }
}

extern "C" void kernel_launch(void* const* d_in, const int* in_sizes, int n_in,
                              void* d_out, int out_size, void* d_ws, size_t ws_size,
                              hipStream_t stream) {
    const float* x     = (const float*)d_in[0];
    const int*   ei    = (const int*)d_in[1];
    const float* W_in  = (const float*)d_in[2];
    const float* b_in  = (const float*)d_in[3];
    const float* Wl    = (const float*)d_in[4];
    const float* bl    = (const float*)d_in[5];
    const float* Wr    = (const float*)d_in[6];
    const float* ln_g  = (const float*)d_in[7];
    const float* ln_b  = (const float*)d_in[8];
    const float* out_g = (const float*)d_in[9];
    const float* out_b = (const float*)d_in[10];

    const int N = in_sizes[0] / D_IN;
    const int E = in_sizes[1] / 2;
    const int* src = ei;
    const int* dst = ei + E;
    const int nbuk = (N + BKT_SIZE - 1) >> BKT_BITS;   // 196, must be <= 256

    char* ws = (char*)d_ws;
    size_t off = 0;
    auto take = [&](size_t bytes) {
        char* p = ws + off;
        off += (bytes + 255) & ~(size_t)255;
        return (void*)p;
    };
    u16*      h0      = (u16*)take((size_t)N * HID * 2);
    u16*      h1      = (u16*)take((size_t)N * HID * 2);
    u16*      aggb    = (u16*)take((size_t)N * HID * 2);
    u8*       hq      = (u8*)take((size_t)N * HID);
    int4*     meta    = (int4*)take((size_t)N * 16);
    int*      ssorted = (int*)take(((size_t)nbuk * BKT_CAP + 64) * 4);
    unsigned* packedA = (unsigned*)take(((size_t)nbuk * BKT_CAP + 64) * 4);
    int*      curA    = (int*)take((size_t)nbuk * 4);

    const int NBLK = (N + 255) / 256;
    const int ABLK = (E + CHUNK - 1) / CHUNK;

    // 1) zero bucket cursors (tiny), then fused proj || phaseA (independent work)
    hipMemsetAsync(curA, 0, (size_t)nbuk * 4, stream);
    proj_phaseA<<<NBLK + ABLK, 256, 0, stream>>>(x, W_in, b_in, h0, hq, N, NBLK,
                                                 src, dst, E, curA, packedA, nbuk);

    // 2) per-bucket CSR finalize (aligned regions)
    phaseB<<<nbuk, 256, 0, stream>>>(packedA, curA, N, ssorted, meta);

    // 3) layers (h0 -> h1 -> h0 -> d_out); hq is the fp8 shadow for gathers
    u16* hc = h0;
    u16* hn = h1;
    for (int l = 0; l < NLAYERS; l++) {
        agg_kernel<<<2048, 256, 0, stream>>>(hq, meta, ssorted, aggb, N);
        const float* wl = Wl + (size_t)l * HID * HID;
        const float* wr = Wr + (size_t)l * HID * HID;
        const float* bb = bl + (size_t)l * HID;
        const float* lg = ln_g + (size_t)l * HID;
        const float* lb = ln_b + (size_t)l * HID;
        if (l == NLAYERS - 1) {
            layer_mfma<true><<<NBLK, 256, 0, stream>>>(hc, aggb, wl, wr, bb, lg, lb,
                                                       out_g, out_b, nullptr, nullptr,
                                                       (float*)d_out, N);
        } else {
            layer_mfma<false><<<NBLK, 256, 0, stream>>>(hc, aggb, wl, wr, bb, lg, lb,
                                                        nullptr, nullptr, hn, hq, nullptr, N);
            u16* tmp = hc; hc = hn; hn = tmp;
        }
    }
}